// Round 1
// baseline (2162.612 us; speedup 1.0000x reference)
//
#include <hip/hip_runtime.h>

#define H 1024
#define FH 4096
#define BSZ 1024
#define T 32

typedef unsigned short u16;
typedef unsigned int u32;
typedef __attribute__((ext_vector_type(8))) short short8;
typedef __attribute__((ext_vector_type(4))) float f32x4;

__device__ __forceinline__ float b2f(u16 u) {
    union { u32 i; float f; } x; x.i = ((u32)u) << 16; return x.f;
}
__device__ __forceinline__ u16 f2b(float f) {
    union { float f; u32 i; } x; x.f = f;
    u32 r = x.i + 0x7fff + ((x.i >> 16) & 1);
    return (u16)(r >> 16);
}
__device__ __forceinline__ float sigm(float x) { return 1.f / (1.f + __expf(-x)); }

// ---------- prep: W_eff = W_hh + W_ih (outer) W_out, cast to bf16 ----------
__global__ void prep_weff_k(const float* __restrict__ Whh, const float* __restrict__ Wih,
                            const float* __restrict__ Wo, u16* __restrict__ weff) {
    int idx = (blockIdx.x * 256 + threadIdx.x) * 8;   // grid 2048
    int r = idx >> 10, k = idx & 1023;
    float wih = Wih[r];
    short8 outv;
#pragma unroll
    for (int e = 0; e < 8; e++) {
        float v = Whh[idx + e] + wih * Wo[k + e];
        outv[e] = (short)f2b(v);
    }
    *(short8*)(weff + idx) = outv;
}

// ---------- prep: c copy, h0->bf16, bias' ----------
__global__ void prep_misc_k(const float* __restrict__ c0, const float* __restrict__ h0,
                            const float* __restrict__ bih, const float* __restrict__ bhh,
                            const float* __restrict__ bo, const float* __restrict__ Wih,
                            float* __restrict__ cbuf, u16* __restrict__ hbuf,
                            float* __restrict__ biasp) {
    int i = (blockIdx.x * 256 + threadIdx.x) * 4;     // grid 1024
#pragma unroll
    for (int e = 0; e < 4; e++) {
        cbuf[i + e] = c0[i + e];
        hbuf[i + e] = f2b(h0[i + e]);
    }
    if (blockIdx.x == 0) {
        for (int b = threadIdx.x; b < FH; b += 256)
            biasp[b] = bih[b] + bhh[b] + bo[0] * Wih[b];
    }
}

// ---------- prep: d0 = in_data - (h0 . Wout + b_out) ----------
__global__ void prep_d0_k(const float* __restrict__ in_data, const float* __restrict__ h0,
                          const float* __restrict__ Wo, const float* __restrict__ bo,
                          float* __restrict__ dd0) {
    int lane = threadIdx.x & 63, wid = threadIdx.x >> 6;   // grid 16 x 256
    for (int rr = 0; rr < 16; ++rr) {
        int m = blockIdx.x * 64 + (wid << 4) + rr;
        const float* hp = h0 + ((u32)m << 10) + lane * 16;
        const float* wp = Wo + lane * 16;
        float s = 0.f;
#pragma unroll
        for (int e = 0; e < 16; e++) s += hp[e] * wp[e];
#pragma unroll
        for (int off = 32; off >= 1; off >>= 1) s += __shfl_xor(s, off, 64);
        if (lane == 0) dd0[m] = in_data[m] - s - bo[0];
    }
}

// ---------- final output column (t = 31) ----------
__global__ void y_last_k(const u16* __restrict__ hin, const float* __restrict__ Wo,
                         const float* __restrict__ bo, float* __restrict__ yout) {
    int lane = threadIdx.x & 63, wid = threadIdx.x >> 6;   // grid 32 x 256
    float bov = bo[0];
    for (int rr = 0; rr < 8; ++rr) {
        int m = blockIdx.x * 32 + (wid << 3) + rr;
        const uint4 h1 = *(const uint4*)(hin + ((u32)m << 10) + lane * 16);
        const uint4 h2 = *(const uint4*)(hin + ((u32)m << 10) + lane * 16 + 8);
        const u16* hp1 = (const u16*)&h1;
        const u16* hp2 = (const u16*)&h2;
        const float* wp = Wo + lane * 16;
        float s = 0.f;
#pragma unroll
        for (int e = 0; e < 8; e++) s += b2f(hp1[e]) * wp[e];
#pragma unroll
        for (int e = 0; e < 8; e++) s += b2f(hp2[e]) * wp[8 + e];
#pragma unroll
        for (int off = 32; off >= 1; off >>= 1) s += __shfl_xor(s, off, 64);
        if (lane == 0) yout[(u32)m * T] = s + bov;
    }
}

// ---------- one LSTM step: gates GEMM (bf16 MFMA) + cell update (+ y of prev h) ----------
__global__ __launch_bounds__(256) void lstm_step_k(
    const u16* __restrict__ hin, u16* __restrict__ hout,
    float* __restrict__ cbuf, const u16* __restrict__ weff,
    const float* __restrict__ biasp, const float* __restrict__ d0,   // d0: only t==0
    const float* __restrict__ Wih, const float* __restrict__ Wo,
    const float* __restrict__ bo, float* __restrict__ yout)          // yout: null at t==0
{
    __shared__ __align__(16) char smem[34816];
    float* gb = (float*)smem;   // [64][132] gates exchange, reused after GEMM

    const int tid = threadIdx.x;
    const int lane = tid & 63, wid = tid >> 6;
    const int wr = wid >> 1, wc = wid & 1;
    const int bx = blockIdx.x;
    const int mb = bx >> 5, jb = bx & 31;
    const int m0 = mb << 7, j0 = jb << 5;

    f32x4 acc[4][4];
#pragma unroll
    for (int i = 0; i < 4; i++)
#pragma unroll
        for (int j = 0; j < 4; j++) acc[i][j] = (f32x4){0.f, 0.f, 0.f, 0.f};

    // staging chunk descriptors: 1024 16B-chunks each for hs(A) and wt(B), 4 per thread
    int crow[4], csub[4], wrow_[4];
#pragma unroll
    for (int i = 0; i < 4; i++) {
        int c_ = tid + i * 256;
        crow[i] = c_ >> 3; csub[i] = c_ & 7;
        int n = crow[i];
        wrow_[i] = ((n >> 5) << 10) + j0 + (n & 31);   // gate-group row in W_eff
    }

    uint4 ph[4], pw[4];
    auto loadt = [&](int kk) {
#pragma unroll
        for (int i = 0; i < 4; i++) {
            ph[i] = *(const uint4*)(hin + ((m0 + crow[i]) << 10) + kk + csub[i] * 8);
            pw[i] = *(const uint4*)(weff + (wrow_[i] << 10) + kk + csub[i] * 8);
        }
    };
    auto writet = [&]() {
#pragma unroll
        for (int i = 0; i < 4; i++) {
            int sb = (crow[i] * 128 + csub[i] * 16) ^ ((crow[i] & 7) << 4);  // XOR swizzle
            *(uint4*)(smem + sb) = ph[i];
            *(uint4*)(smem + 16384 + sb) = pw[i];
        }
    };

    loadt(0); writet();

    const int rl = lane & 15, sl = lane >> 4;
    for (int it = 0; it < 16; ++it) {
        __syncthreads();                       // tile it visible
        if (it < 15) loadt((it + 1) * 64);     // T14: issue next loads early
#pragma unroll
        for (int ks = 0; ks < 2; ++ks) {
            short8 af[4], bg[4];
#pragma unroll
            for (int im = 0; im < 4; ++im) {
                int row = (wr << 6) + (im << 4) + rl;
                int sb = (row * 128 + (ks * 4 + sl) * 16) ^ ((row & 7) << 4);
                af[im] = *(const short8*)(smem + sb);
            }
#pragma unroll
            for (int in_ = 0; in_ < 4; ++in_) {
                int row = (wc << 6) + (in_ << 4) + rl;
                int sb = (row * 128 + (ks * 4 + sl) * 16) ^ ((row & 7) << 4);
                bg[in_] = *(const short8*)(smem + 16384 + sb);
            }
#pragma unroll
            for (int im = 0; im < 4; ++im)
#pragma unroll
                for (int in_ = 0; in_ < 4; ++in_)
                    acc[im][in_] = __builtin_amdgcn_mfma_f32_16x16x32_bf16(
                        af[im], bg[in_], acc[im][in_], 0, 0, 0);
        }
        __syncthreads();                       // compute done
        if (it < 15) writet();                 // T14: write-late into LDS
    }

    // ---------- epilogue: two 64-row passes through LDS, cell update ----------
    const int jj = tid & 31, mg = tid >> 5;
    const int j = j0 + jj;
    const float bi = biasp[j], bff = biasp[H + j], bgg = biasp[2 * H + j], boo = biasp[3 * H + j];
    float wi = 0, wf = 0, wg = 0, wo = 0;
    const bool isd0 = (d0 != nullptr);
    if (isd0) { wi = Wih[j]; wf = Wih[H + j]; wg = Wih[2 * H + j]; wo = Wih[3 * H + j]; }

    for (int p = 0; p < 2; ++p) {
        __syncthreads();
        if (wr == p) {
#pragma unroll
            for (int im = 0; im < 4; ++im)
#pragma unroll
                for (int in_ = 0; in_ < 4; ++in_)
#pragma unroll
                    for (int q = 0; q < 4; ++q) {
                        int m_rel = (im << 4) + (sl << 2) + q;
                        int n = (wc << 6) + (in_ << 4) + rl;
                        gb[m_rel * 132 + n] = acc[im][in_][q];
                    }
        }
        __syncthreads();
#pragma unroll
        for (int q = 0; q < 8; ++q) {
            int m_rel = (mg << 3) + q;
            int m = m0 + (p << 6) + m_rel;
            const float* gr = gb + m_rel * 132;
            float gi = gr[jj] + bi;
            float gf_ = gr[32 + jj] + bff;
            float gg_ = gr[64 + jj] + bgg;
            float go_ = gr[96 + jj] + boo;
            if (isd0) {
                float d = d0[m];
                gi += d * wi; gf_ += d * wf; gg_ += d * wg; go_ += d * wo;
            }
            float cv = cbuf[((u32)m << 10) + j];
            float cn = sigm(gf_) * cv + sigm(gi) * tanhf(gg_);
            float hn = sigm(go_) * tanhf(cn);
            cbuf[((u32)m << 10) + j] = cn;
            hout[((u32)m << 10) + j] = f2b(hn);
        }
    }

    // ---------- opportunistic output: y_{t-1} from h_in (jb==0 blocks) ----------
    if (jb == 0 && yout) {
        float bov = bo[0];
        for (int rr = 0; rr < 32; ++rr) {
            int m = m0 + (wid << 5) + rr;
            const uint4 h1 = *(const uint4*)(hin + ((u32)m << 10) + lane * 16);
            const uint4 h2 = *(const uint4*)(hin + ((u32)m << 10) + lane * 16 + 8);
            const u16* hp1 = (const u16*)&h1;
            const u16* hp2 = (const u16*)&h2;
            const float* wp = Wo + lane * 16;
            float s = 0.f;
#pragma unroll
            for (int e = 0; e < 8; e++) s += b2f(hp1[e]) * wp[e];
#pragma unroll
            for (int e = 0; e < 8; e++) s += b2f(hp2[e]) * wp[8 + e];
#pragma unroll
            for (int off = 32; off >= 1; off >>= 1) s += __shfl_xor(s, off, 64);
            if (lane == 0) yout[(u32)m * T] = s + bov;
        }
    }
}

extern "C" void kernel_launch(void* const* d_in, const int* in_sizes, int n_in,
                              void* d_out, int out_size, void* d_ws, size_t ws_size,
                              hipStream_t stream) {
    const float* in_data = (const float*)d_in[0];
    // d_in[1] = batch_size (int scalar), unused
    const float* h0  = (const float*)d_in[2];
    const float* c0  = (const float*)d_in[3];
    const float* Wih = (const float*)d_in[4];
    const float* Whh = (const float*)d_in[5];
    const float* bih = (const float*)d_in[6];
    const float* bhh = (const float*)d_in[7];
    const float* Wo  = (const float*)d_in[8];
    const float* bo  = (const float*)d_in[9];
    float* out = (float*)d_out;
    char* ws = (char*)d_ws;

    u16*   weff  = (u16*)ws;                          // 8 MB  W_eff bf16 (4096x1024)
    u16*   hb0   = (u16*)(ws + (8u  << 20));          // 2 MB  h ping
    u16*   hb1   = (u16*)(ws + (10u << 20));          // 2 MB  h pong
    float* cbuf  = (float*)(ws + (12u << 20));        // 4 MB  c state fp32
    float* biasp = (float*)(ws + (16u << 20));        // 16 KB bias'
    float* dd0   = (float*)(ws + (16u << 20) + 16384);// 4 KB  step-0 correction

    hipLaunchKernelGGL(prep_weff_k, dim3(2048), dim3(256), 0, stream, Whh, Wih, Wo, weff);
    hipLaunchKernelGGL(prep_misc_k, dim3(1024), dim3(256), 0, stream,
                       c0, h0, bih, bhh, bo, Wih, cbuf, hb0, biasp);
    hipLaunchKernelGGL(prep_d0_k, dim3(16), dim3(256), 0, stream, in_data, h0, Wo, bo, dd0);

    for (int t = 0; t < T; ++t) {
        const u16* hin = (t & 1) ? hb1 : hb0;
        u16* hout_     = (t & 1) ? hb0 : hb1;
        hipLaunchKernelGGL(lstm_step_k, dim3(256), dim3(256), 0, stream,
                           hin, hout_, cbuf, weff, biasp,
                           (t == 0) ? dd0 : (const float*)nullptr,
                           Wih, Wo, bo,
                           (t == 0) ? (float*)nullptr : (out + (t - 1)));
    }
    // t=31 wrote hout = hb0 (t odd); final column from it
    hipLaunchKernelGGL(y_last_k, dim3(32), dim3(256), 0, stream, hb0, Wo, bo, out + 31);
}

// Round 2
// 1711.810 us; speedup vs baseline: 1.2633x; 1.2633x over previous
//
#include <hip/hip_runtime.h>

#define H 1024
#define FH 4096
#define T 32

typedef unsigned short u16;
typedef unsigned int u32;
typedef __attribute__((ext_vector_type(8))) short short8;
typedef __attribute__((ext_vector_type(4))) float f32x4;

__device__ __forceinline__ float b2f(u16 u) {
    union { u32 i; float f; } x; x.i = ((u32)u) << 16; return x.f;
}
__device__ __forceinline__ u16 f2b(float f) {
    union { float f; u32 i; } x; x.f = f;
    u32 r = x.i + 0x7fff + ((x.i >> 16) & 1);
    return (u16)(r >> 16);
}
__device__ __forceinline__ float sigm(float x) { return 1.f / (1.f + __expf(-x)); }

// ---------- prep: W_eff = W_hh + W_ih (outer) W_out, cast to bf16 ----------
__global__ void prep_weff_k(const float* __restrict__ Whh, const float* __restrict__ Wih,
                            const float* __restrict__ Wo, u16* __restrict__ weff) {
    int idx = (blockIdx.x * 256 + threadIdx.x) * 8;   // grid 2048
    int r = idx >> 10, k = idx & 1023;
    float wih = Wih[r];
    short8 outv;
#pragma unroll
    for (int e = 0; e < 8; e++) {
        float v = Whh[idx + e] + wih * Wo[k + e];
        outv[e] = (short)f2b(v);
    }
    *(short8*)(weff + idx) = outv;
}

// ---------- prep: h0->bf16, bias', out = b_out ----------
__global__ void prep_misc_k(const float* __restrict__ h0, const float* __restrict__ bih,
                            const float* __restrict__ bhh, const float* __restrict__ bo,
                            const float* __restrict__ Wih,
                            u16* __restrict__ hbuf, float* __restrict__ biasp,
                            float* __restrict__ out) {
    int i = (blockIdx.x * 256 + threadIdx.x) * 4;     // grid 1024
#pragma unroll
    for (int e = 0; e < 4; e++) hbuf[i + e] = f2b(h0[i + e]);
    if (blockIdx.x == 0) {
        for (int b = threadIdx.x; b < FH; b += 256)
            biasp[b] = bih[b] + bhh[b] + bo[0] * Wih[b];
    }
    if (blockIdx.x < 32) {                            // out: 1024*32 floats = b_out
        float b0 = bo[0];
        int o = blockIdx.x * 1024 + threadIdx.x * 4;
#pragma unroll
        for (int e = 0; e < 4; e++) out[o + e] = b0;
    }
}

// ---------- prep: d0 = in_data - (h0 . Wout + b_out) ----------
__global__ void prep_d0_k(const float* __restrict__ in_data, const float* __restrict__ h0,
                          const float* __restrict__ Wo, const float* __restrict__ bo,
                          float* __restrict__ dd0) {
    int lane = threadIdx.x & 63, wid = threadIdx.x >> 6;   // grid 16 x 256
    for (int rr = 0; rr < 16; ++rr) {
        int m = blockIdx.x * 64 + (wid << 4) + rr;
        const float* hp = h0 + ((u32)m << 10) + lane * 16;
        const float* wp = Wo + lane * 16;
        float s = 0.f;
#pragma unroll
        for (int e = 0; e < 16; e++) s += hp[e] * wp[e];
#pragma unroll
        for (int off = 32; off >= 1; off >>= 1) s += __shfl_xor(s, off, 64);
        if (lane == 0) dd0[m] = in_data[m] - s - bo[0];
    }
}

// ---------- persistent: all 32 LSTM steps, group barriers per mb-row-group ----------
__global__ __launch_bounds__(512) void lstm_persist_k(
    const u16* __restrict__ weff, u16* __restrict__ hb0, u16* __restrict__ hb1,
    const float* __restrict__ biasp, const float* __restrict__ dd0,
    const float* __restrict__ Wih, const float* __restrict__ Wo,
    const float* __restrict__ c0, float* __restrict__ out, u32* __restrict__ cnt)
{
    __shared__ __align__(16) char smem[65536];   // stage A[0:32K], B[32K:64K]; gb overlays
    float* gb = (float*)smem;                    // [64][132] fp32 gates exchange

    const int tid = threadIdx.x;
    const int lane = tid & 63, wid = tid >> 6;
    const int wr = wid >> 2, wc = wid & 3;       // 8 waves: 2 (m) x 4 (gate-col)
    const int bx = blockIdx.x;
    const int mb = bx >> 5, jb = bx & 31;        // 8 row-groups x 32 col-slices
    const int m0 = mb << 7, j0 = jb << 5;
    const int rl = lane & 15, sl = lane >> 4;
    const int jj = tid & 31, grp = tid >> 5;     // epilogue mapping
    const int j = j0 + jj;

    // persistent per-thread state
    const float bs0 = biasp[j], bs1 = biasp[H + j], bs2 = biasp[2 * H + j], bs3 = biasp[3 * H + j];
    const float wi0 = Wih[j], wi1 = Wih[H + j], wi2 = Wih[2 * H + j], wi3 = Wih[3 * H + j];
    const float woj = Wo[j];
    float c_reg[8];
#pragma unroll
    for (int p = 0; p < 2; ++p)
#pragma unroll
        for (int q = 0; q < 4; ++q)
            c_reg[p * 4 + q] = c0[(u32)(m0 + p * 64 + grp * 4 + q) * H + j];

    // staging descriptors (BK=128): 2048 16B-chunks per tile, 4 per thread
    int crow[4], csub[4], wrow_[4];
#pragma unroll
    for (int i = 0; i < 4; i++) {
        int c_ = tid + i * 512;
        crow[i] = c_ >> 4; csub[i] = c_ & 15;
        wrow_[i] = ((crow[i] >> 5) << 10) + j0 + (crow[i] & 31);
    }

    for (int s = 0; s < T; ++s) {
        const u16* hin = (s & 1) ? hb1 : hb0;
        u16* hout = (s & 1) ? hb0 : hb1;

        f32x4 acc[4][2];
#pragma unroll
        for (int im = 0; im < 4; im++)
#pragma unroll
            for (int in_ = 0; in_ < 2; in_++) acc[im][in_] = (f32x4){0.f, 0.f, 0.f, 0.f};

        uint4 ph[4], pw[4];
        auto loadt = [&](int kk) {
#pragma unroll
            for (int i = 0; i < 4; i++) {
                ph[i] = *(const uint4*)(hin + ((u32)(m0 + crow[i]) << 10) + kk + csub[i] * 8);
                pw[i] = *(const uint4*)(weff + ((u32)wrow_[i] << 10) + kk + csub[i] * 8);
            }
        };
        auto writet = [&]() {
#pragma unroll
            for (int i = 0; i < 4; i++) {
                int sb = (crow[i] * 256 + csub[i] * 16) ^ ((crow[i] & 15) << 4);  // XOR swizzle
                *(uint4*)(smem + sb) = ph[i];
                *(uint4*)(smem + 32768 + sb) = pw[i];
            }
        };

        loadt(0); writet();

        for (int it = 0; it < 8; ++it) {
            __syncthreads();                       // tile visible
            if (it < 7) loadt((it + 1) * 128);     // T14: issue next loads early
#pragma unroll
            for (int ks = 0; ks < 4; ++ks) {
                short8 af[4], bg[2];
#pragma unroll
                for (int im = 0; im < 4; ++im) {
                    int row = (wr << 6) + (im << 4) + rl;
                    int sb = (row * 256 + (ks * 4 + sl) * 16) ^ ((row & 15) << 4);
                    af[im] = *(const short8*)(smem + sb);
                }
#pragma unroll
                for (int in_ = 0; in_ < 2; ++in_) {
                    int row = (wc << 5) + (in_ << 4) + rl;
                    int sb = (row * 256 + (ks * 4 + sl) * 16) ^ ((row & 15) << 4);
                    bg[in_] = *(const short8*)(smem + 32768 + sb);
                }
#pragma unroll
                for (int im = 0; im < 4; ++im)
#pragma unroll
                    for (int in_ = 0; in_ < 2; ++in_)
                        acc[im][in_] = __builtin_amdgcn_mfma_f32_16x16x32_bf16(
                            af[im], bg[in_], acc[im][in_], 0, 0, 0);
            }
            __syncthreads();                       // compute done
            if (it < 7) writet();                  // T14: write-late
        }

        // ---------- epilogue: two 64-row passes, c in regs, y partial via shfl+atomic ----------
#pragma unroll
        for (int p = 0; p < 2; ++p) {
            __syncthreads();
            if (wr == p) {
#pragma unroll
                for (int im = 0; im < 4; ++im)
#pragma unroll
                    for (int in_ = 0; in_ < 2; ++in_)
#pragma unroll
                        for (int q = 0; q < 4; ++q)
                            gb[(im * 16 + sl * 4 + q) * 132 + (wc << 5) + (in_ << 4) + rl]
                                = acc[im][in_][q];
            }
            __syncthreads();
#pragma unroll
            for (int q = 0; q < 4; ++q) {
                int m_loc = grp * 4 + q;
                int m_abs = m0 + p * 64 + m_loc;
                const float* gr = gb + m_loc * 132;
                float gi  = gr[jj] + bs0;
                float gf_ = gr[32 + jj] + bs1;
                float gg_ = gr[64 + jj] + bs2;
                float go_ = gr[96 + jj] + bs3;
                if (s == 0) {
                    float d = dd0[m_abs];
                    gi += d * wi0; gf_ += d * wi1; gg_ += d * wi2; go_ += d * wi3;
                }
                float cv = c_reg[p * 4 + q];
                float cn = sigm(gf_) * cv + sigm(gi) * tanhf(gg_);
                float hn = sigm(go_) * tanhf(cn);
                c_reg[p * 4 + q] = cn;
                hout[((u32)m_abs << 10) + j] = f2b(hn);
                float yp = hn * woj;               // partial y over this block's 32 cols
                yp += __shfl_xor(yp, 16, 32);
                yp += __shfl_xor(yp, 8, 32);
                yp += __shfl_xor(yp, 4, 32);
                yp += __shfl_xor(yp, 2, 32);
                yp += __shfl_xor(yp, 1, 32);
                if (jj == 0) atomicAdd(out + (u32)m_abs * T + s, yp);
            }
        }

        // ---------- group barrier: 32 blocks sharing mb ----------
        if (s < T - 1) {
            __syncthreads();
            if (tid == 0) {
                __threadfence();                                       // release h writes
                u32* cc = cnt + ((u32)(s * 8 + mb) << 4);              // 64B-spaced counters
                __hip_atomic_fetch_add(cc, 1u, __ATOMIC_RELAXED, __HIP_MEMORY_SCOPE_AGENT);
                while (__hip_atomic_load(cc, __ATOMIC_RELAXED, __HIP_MEMORY_SCOPE_AGENT) < 32u)
                    __builtin_amdgcn_s_sleep(2);
                __threadfence();                                       // acquire peers' h
            }
            __syncthreads();
        }
    }
}

extern "C" void kernel_launch(void* const* d_in, const int* in_sizes, int n_in,
                              void* d_out, int out_size, void* d_ws, size_t ws_size,
                              hipStream_t stream) {
    const float* in_data = (const float*)d_in[0];
    // d_in[1] = batch_size (int scalar), unused
    const float* h0  = (const float*)d_in[2];
    const float* c0  = (const float*)d_in[3];
    const float* Wih = (const float*)d_in[4];
    const float* Whh = (const float*)d_in[5];
    const float* bih = (const float*)d_in[6];
    const float* bhh = (const float*)d_in[7];
    const float* Wo  = (const float*)d_in[8];
    const float* bo  = (const float*)d_in[9];
    float* out = (float*)d_out;
    char* ws = (char*)d_ws;

    u16*   weff  = (u16*)ws;                            // 8 MB  W_eff bf16 (4096x1024)
    u16*   hb0   = (u16*)(ws + (8u  << 20));            // 2 MB  h ping
    u16*   hb1   = (u16*)(ws + (10u << 20));            // 2 MB  h pong
    float* biasp = (float*)(ws + (12u << 20));          // 16 KB bias'
    float* dd0   = (float*)(ws + (12u << 20) + 16384);  // 4 KB  step-0 correction
    u32*   cnt   = (u32*)(ws + (12u << 20) + 32768);    // 16 KB barrier counters

    hipMemsetAsync(cnt, 0, 32 * 8 * 16 * sizeof(u32), stream);
    hipLaunchKernelGGL(prep_weff_k, dim3(2048), dim3(256), 0, stream, Whh, Wih, Wo, weff);
    hipLaunchKernelGGL(prep_misc_k, dim3(1024), dim3(256), 0, stream,
                       h0, bih, bhh, bo, Wih, hb0, biasp, out);
    hipLaunchKernelGGL(prep_d0_k, dim3(16), dim3(256), 0, stream, in_data, h0, Wo, bo, dd0);

    hipLaunchKernelGGL(lstm_persist_k, dim3(256), dim3(512), 0, stream,
                       weff, hb0, hb1, biasp, dd0, Wih, Wo, c0, out, cnt);
}

// Round 3
// 535.081 us; speedup vs baseline: 4.0417x; 3.1992x over previous
//
#include <hip/hip_runtime.h>

#define H 1024
#define FH 4096
#define T 32

typedef unsigned short u16;
typedef unsigned int u32;
typedef __attribute__((ext_vector_type(8))) short short8;
typedef __attribute__((ext_vector_type(4))) u32 u32x4;
typedef __attribute__((ext_vector_type(4))) float f32x4;

#define HSZ (1u << 20)   // u16 elements per h buffer (2 MB)

__device__ __forceinline__ u16 f2b(float f) {
    union { float f; u32 i; } x; x.f = f;
    u32 r = x.i + 0x7fff + ((x.i >> 16) & 1);
    return (u16)(r >> 16);
}
__device__ __forceinline__ float b2f(u16 u) {
    union { u32 i; float f; } x; x.i = ((u32)u) << 16; return x.f;
}
__device__ __forceinline__ float sigm(float x) { return 1.f / (1.f + __expf(-x)); }

// ---------- prep: W_eff = W_hh + W_ih (outer) W_out, cast to bf16 ----------
__global__ void prep_weff_k(const float* __restrict__ Whh, const float* __restrict__ Wih,
                            const float* __restrict__ Wo, u16* __restrict__ weff) {
    int idx = (blockIdx.x * 256 + threadIdx.x) * 8;   // grid 2048
    int r = idx >> 10, k = idx & 1023;
    float wih = Wih[r];
    short8 outv;
#pragma unroll
    for (int e = 0; e < 8; e++) {
        float v = Whh[idx + e] + wih * Wo[k + e];
        outv[e] = (short)f2b(v);
    }
    *(short8*)(weff + idx) = outv;
}

// ---------- prep: h0->bf16 (buf0), bias', out = b_out ----------
__global__ void prep_misc_k(const float* __restrict__ h0, const float* __restrict__ bih,
                            const float* __restrict__ bhh, const float* __restrict__ bo,
                            const float* __restrict__ Wih,
                            u16* __restrict__ hbase, float* __restrict__ biasp,
                            float* __restrict__ out) {
    int i = (blockIdx.x * 256 + threadIdx.x) * 4;     // grid 1024
#pragma unroll
    for (int e = 0; e < 4; e++) hbase[i + e] = f2b(h0[i + e]);
    if (blockIdx.x == 0) {
        for (int b = threadIdx.x; b < FH; b += 256)
            biasp[b] = bih[b] + bhh[b] + bo[0] * Wih[b];
    }
    if (blockIdx.x < 32) {                            // out: 1024*32 floats = b_out
        float b0 = bo[0];
        int o = blockIdx.x * 1024 + threadIdx.x * 4;
#pragma unroll
        for (int e = 0; e < 4; e++) out[o + e] = b0;
    }
}

// ---------- prep: d0 = in_data - (h0 . Wout + b_out) ----------
__global__ void prep_d0_k(const float* __restrict__ in_data, const float* __restrict__ h0,
                          const float* __restrict__ Wo, const float* __restrict__ bo,
                          float* __restrict__ dd0) {
    int lane = threadIdx.x & 63, wid = threadIdx.x >> 6;   // grid 64 x 256
    for (int rr = 0; rr < 4; ++rr) {
        int m = blockIdx.x * 16 + (wid << 2) + rr;
        const float* hp = h0 + ((u32)m << 10) + lane * 16;
        const float* wp = Wo + lane * 16;
        float s = 0.f;
#pragma unroll
        for (int e = 0; e < 16; e++) s += hp[e] * wp[e];
#pragma unroll
        for (int off = 32; off >= 1; off >>= 1) s += __shfl_xor(s, off, 64);
        if (lane == 0) dd0[m] = in_data[m] - s - bo[0];
    }
}

// ---------- persistent: all 32 steps; no cache-maintenance sync ----------
// COH=false (rotation): 33 h buffers, plain cached A-loads (virgin addresses each step)
// COH=true  (2 buffers): A-loads via sc0 sc1 bypass (always read coherence point)
// h stores are always agent write-through; barrier = relaxed agent atomics only.
template<bool COH>
__global__ __launch_bounds__(512) void lstm_persist_k(
    const u16* __restrict__ weff, u16* __restrict__ hbase,
    const float* __restrict__ biasp, const float* __restrict__ dd0,
    const float* __restrict__ Wih, const float* __restrict__ Wo,
    const float* __restrict__ c0, float* __restrict__ out, u32* __restrict__ cnt)
{
    __shared__ __align__(16) char smem[65536];   // stage A[0:32K], B[32K:64K]; gb overlays
    float* gb = (float*)smem;                    // [64][132] fp32 gates exchange

    const int tid = threadIdx.x;
    const int lane = tid & 63, wid = tid >> 6;
    const int wr = wid >> 2, wc = wid & 3;       // 8 waves: 2 (m) x 4 (gate-col)
    const int bx = blockIdx.x;
    const int mb = (bx >> 3) & 7;                // row-group (spans XCDs)
    const int jb = (bx & 7) * 4 + (bx >> 6);     // col-slice, clustered per XCD (weff L2-hot)
    const int m0 = mb << 7, j0 = jb << 5;
    const int rl = lane & 15, sl = lane >> 4;
    const int jj = tid & 31, grp = tid >> 5;     // epilogue mapping
    const int j = j0 + jj;

    // persistent per-thread state
    const float bs0 = biasp[j], bs1 = biasp[H + j], bs2 = biasp[2 * H + j], bs3 = biasp[3 * H + j];
    const float wi0 = Wih[j], wi1 = Wih[H + j], wi2 = Wih[2 * H + j], wi3 = Wih[3 * H + j];
    const float woj = Wo[j];
    float c_reg[8];
#pragma unroll
    for (int p = 0; p < 2; ++p)
#pragma unroll
        for (int q = 0; q < 4; ++q)
            c_reg[p * 4 + q] = c0[(u32)(m0 + p * 64 + grp * 4 + q) * H + j];

    // staging descriptors (BK=128): 2048 16B-chunks per tile, 4 per thread
    int crow[4], csub[4], wrow_[4];
#pragma unroll
    for (int i = 0; i < 4; i++) {
        int c_ = tid + i * 512;
        crow[i] = c_ >> 4; csub[i] = c_ & 15;
        wrow_[i] = ((crow[i] >> 5) << 10) + j0 + (crow[i] & 31);
    }

    for (int s = 0; s < T; ++s) {
        const u16* hin = hbase + (u32)(COH ? (s & 1) : s) * HSZ;
        u16* hout      = hbase + (u32)(COH ? ((s + 1) & 1) : (s + 1)) * HSZ;

        f32x4 acc[4][2];
#pragma unroll
        for (int im = 0; im < 4; im++)
#pragma unroll
            for (int in_ = 0; in_ < 2; in_++) acc[im][in_] = (f32x4){0.f, 0.f, 0.f, 0.f};

        u32x4 ph[4], pw[4];
        auto loadt = [&](int kk) {
#pragma unroll
            for (int i = 0; i < 4; i++) {
                const u16* pa = hin + ((u32)(m0 + crow[i]) << 10) + kk + csub[i] * 8;
                if constexpr (COH) {
                    asm volatile("global_load_dwordx4 %0, %1, off sc0 sc1"
                                 : "=v"(ph[i]) : "v"(pa));
                } else {
                    ph[i] = *(const u32x4*)pa;
                }
                pw[i] = *(const u32x4*)(weff + ((u32)wrow_[i] << 10) + kk + csub[i] * 8);
            }
        };
        auto writet = [&]() {
            if constexpr (COH) {
                asm volatile("s_waitcnt vmcnt(0)" ::: "memory");
                __builtin_amdgcn_sched_barrier(0);
            }
#pragma unroll
            for (int i = 0; i < 4; i++) {
                int sb = (crow[i] * 256 + csub[i] * 16) ^ ((crow[i] & 15) << 4);  // XOR swizzle
                *(u32x4*)(smem + sb) = ph[i];
                *(u32x4*)(smem + 32768 + sb) = pw[i];
            }
        };

        loadt(0); writet();

        for (int it = 0; it < 8; ++it) {
            __syncthreads();                       // tile visible
            if (it < 7) loadt((it + 1) * 128);     // T14: issue next loads early
#pragma unroll
            for (int ks = 0; ks < 4; ++ks) {
                short8 af[4], bg[2];
#pragma unroll
                for (int im = 0; im < 4; ++im) {
                    int row = (wr << 6) + (im << 4) + rl;
                    int sb = (row * 256 + (ks * 4 + sl) * 16) ^ ((row & 15) << 4);
                    af[im] = *(const short8*)(smem + sb);
                }
#pragma unroll
                for (int in_ = 0; in_ < 2; ++in_) {
                    int row = (wc << 5) + (in_ << 4) + rl;
                    int sb = (row * 256 + (ks * 4 + sl) * 16) ^ ((row & 15) << 4);
                    bg[in_] = *(const short8*)(smem + 32768 + sb);
                }
#pragma unroll
                for (int im = 0; im < 4; ++im)
#pragma unroll
                    for (int in_ = 0; in_ < 2; ++in_)
                        acc[im][in_] = __builtin_amdgcn_mfma_f32_16x16x32_bf16(
                            af[im], bg[in_], acc[im][in_], 0, 0, 0);
            }
            __syncthreads();                       // compute done
            if (it < 7) writet();                  // T14: write-late
        }

        // ---------- epilogue: two 64-row passes, c in regs ----------
#pragma unroll
        for (int p = 0; p < 2; ++p) {
            __syncthreads();
            if (wr == p) {
#pragma unroll
                for (int im = 0; im < 4; ++im)
#pragma unroll
                    for (int in_ = 0; in_ < 2; ++in_)
#pragma unroll
                        for (int q = 0; q < 4; ++q)
                            gb[(im * 16 + sl * 4 + q) * 132 + (wc << 5) + (in_ << 4) + rl]
                                = acc[im][in_][q];
            }
            __syncthreads();
#pragma unroll
            for (int q = 0; q < 4; ++q) {
                int m_loc = grp * 4 + q;
                int m_abs = m0 + p * 64 + m_loc;
                const float* gr = gb + m_loc * 132;
                float gi  = gr[jj] + bs0;
                float gf_ = gr[32 + jj] + bs1;
                float gg_ = gr[64 + jj] + bs2;
                float go_ = gr[96 + jj] + bs3;
                if (s == 0) {
                    float d = dd0[m_abs];
                    gi += d * wi0; gf_ += d * wi1; gg_ += d * wi2; go_ += d * wi3;
                }
                float cv = c_reg[p * 4 + q];
                float cn = sigm(gf_) * cv + sigm(gi) * tanhf(gg_);
                float hn = sigm(go_) * tanhf(cn);
                c_reg[p * 4 + q] = cn;

                // h store: pack 2 bf16 -> u32, agent write-through (MALL-visible, no fence)
                u32 hv = (u32)f2b(hn);
                u32 nb = __shfl_down(hv, 1, 32);
                if ((jj & 1) == 0) {
                    u32* hp = (u32*)(hout + (((u32)m_abs << 10) + j));
                    __hip_atomic_store(hp, (nb << 16) | hv,
                                       __ATOMIC_RELAXED, __HIP_MEMORY_SCOPE_AGENT);
                }

                // y partial over this block's 32 cols
                float yp = hn * woj;
                yp += __shfl_xor(yp, 16, 32);
                yp += __shfl_xor(yp, 8, 32);
                yp += __shfl_xor(yp, 4, 32);
                yp += __shfl_xor(yp, 2, 32);
                yp += __shfl_xor(yp, 1, 32);
                if (jj == 0)
                    __hip_atomic_fetch_add(out + (u32)m_abs * T + s, yp,
                                           __ATOMIC_RELAXED, __HIP_MEMORY_SCOPE_AGENT);
            }
        }

        // ---------- group barrier: 32 blocks sharing mb; no cache maintenance ----------
        if (s < T - 1) {
            __syncthreads();   // compiler drains vmcnt before s_barrier -> h stores at MALL
            if (tid == 0) {
                u32* cc = cnt + ((u32)(s * 8 + mb) << 4);          // 64B-spaced counters
                __hip_atomic_fetch_add(cc, 1u, __ATOMIC_RELAXED, __HIP_MEMORY_SCOPE_AGENT);
                while (__hip_atomic_load(cc, __ATOMIC_RELAXED, __HIP_MEMORY_SCOPE_AGENT) < 32u)
                    __builtin_amdgcn_s_sleep(2);
            }
            __syncthreads();
        }
    }
}

extern "C" void kernel_launch(void* const* d_in, const int* in_sizes, int n_in,
                              void* d_out, int out_size, void* d_ws, size_t ws_size,
                              hipStream_t stream) {
    const float* in_data = (const float*)d_in[0];
    // d_in[1] = batch_size (int scalar), unused
    const float* h0  = (const float*)d_in[2];
    const float* c0  = (const float*)d_in[3];
    const float* Wih = (const float*)d_in[4];
    const float* Whh = (const float*)d_in[5];
    const float* bih = (const float*)d_in[6];
    const float* bhh = (const float*)d_in[7];
    const float* Wo  = (const float*)d_in[8];
    const float* bo  = (const float*)d_in[9];
    float* out = (float*)d_out;
    char* ws = (char*)d_ws;

    u16*   weff  = (u16*)ws;                            // 8 MB   W_eff bf16 (4096x1024)
    float* biasp = (float*)(ws + (8u << 20));           // 16 KB  bias'
    float* dd0   = (float*)(ws + (8u << 20) + 16384);   // 4 KB   step-0 correction
    u32*   cnt   = (u32*)(ws + (8u << 20) + 32768);     // 16 KB  barrier counters
    u16*   hbase = (u16*)(ws + (8u << 20) + 65536);     // 2 MB x (33 rot / 2 coh)

    // rotation path needs 8MB + 64KB + 33*2MB = ~74.1 MB
    bool rot = ws_size >= ((size_t)76 << 20);

    hipMemsetAsync(cnt, 0, 32 * 8 * 16 * sizeof(u32), stream);
    hipLaunchKernelGGL(prep_weff_k, dim3(2048), dim3(256), 0, stream, Whh, Wih, Wo, weff);
    hipLaunchKernelGGL(prep_misc_k, dim3(1024), dim3(256), 0, stream,
                       h0, bih, bhh, bo, Wih, hbase, biasp, out);
    hipLaunchKernelGGL(prep_d0_k, dim3(64), dim3(256), 0, stream, in_data, h0, Wo, bo, dd0);

    if (rot)
        hipLaunchKernelGGL((lstm_persist_k<false>), dim3(256), dim3(512), 0, stream,
                           weff, hbase, biasp, dd0, Wih, Wo, c0, out, cnt);
    else
        hipLaunchKernelGGL((lstm_persist_k<true>), dim3(256), dim3(512), 0, stream,
                           weff, hbase, biasp, dd0, Wih, Wo, c0, out, cnt);
}